// Round 3
// baseline (198.753 us; speedup 1.0000x reference)
//
#include <hip/hip_runtime.h>
#include <hip/hip_bf16.h>

// Problem geometry
#define E_CNT  256
#define D_IN   15
#define HDIM   128
#define BATCH  8192
#define ROWSPG 2048                 // batch rows per workgroup
#define NRG    (BATCH / ROWSPG)     // 4 row-groups -> grid = 1024 blocks
#define NCHUNK (ROWSPG / 32)        // 64 chunks of 32 rows per WG (16 per wave)
#define SW1    24                   // w1t row stride in shorts (48B, 16B-aligned)
#define SW2    152                  // w2t row stride in shorts (304B, 16B-aligned): 128 W2T + b2@128 + 0-pad

typedef float f32x16 __attribute__((ext_vector_type(16)));
typedef short bf16x8 __attribute__((ext_vector_type(8)));
typedef unsigned int uint4v __attribute__((ext_vector_type(4)));

#define MFMA(a, b, c) __builtin_amdgcn_mfma_f32_32x32x16_bf16((a), (b), (c), 0, 0, 0)

static __device__ inline short f2bf(float f) {
    __hip_bfloat16 h = __float2bfloat16(f);
    return __builtin_bit_cast(short, h);
}

static __device__ inline float sg(float z) {
    // sigmoid: 1/(1+exp(-z)) = rcp(1 + 2^(-z*log2e)); correct at +-inf limits
    float e = __builtin_amdgcn_exp2f(z * -1.44269504088896341f);
    return __builtin_amdgcn_rcpf(1.0f + e);
}

// Pack two sigmoids into one dword of 2x bf16. Written as scalar casts + or:
// the compiler fuses this to v_cvt_pk_bf16_f32 (learn_hip m240) — no inline asm.
static __device__ inline unsigned sgpack2(float lo, float hi_) {
    unsigned a = (unsigned)(unsigned short)f2bf(sg(lo));
    unsigned b = (unsigned)(unsigned short)f2bf(sg(hi_));
    return a | (b << 16);
}

// v_permlane32_swap_b32 a, b:
// after: a = {lanes<32: a_lo, lanes>=32: b_lo}; b = {lanes<32: a_hi, lanes>=32: b_hi}
static __device__ inline void pl32swap(unsigned &a, unsigned &b) {
#if __has_builtin(__builtin_amdgcn_permlane32_swap)
    auto r = __builtin_amdgcn_permlane32_swap(a, b, false, false);
    a = (unsigned)r[0];
    b = (unsigned)r[1];
#else
    asm volatile("v_permlane32_swap_b32 %0, %1" : "+v"(a), "+v"(b));
#endif
}

static __device__ inline f32x16 zero16() {
    f32x16 z;
#pragma unroll
    for (int i = 0; i < 16; ++i) z[i] = 0.0f;
    return z;
}

// From a 32x32 C-tile accumulator (col = lane&31 = batch, row = (reg&3)+8*(reg>>2)+4*(lane>>5)),
// apply sigmoid and produce the two B-frags (k = 16t + (lane>>5)*8 + j) covering
// rows 0..15 (f0) and 16..31 (f1). Derivation: B-frag element j=4*j1+j0 on half hi_dst
// needs tile row 16t + 8*hi_dst + 4*j1 + j0 = acc reg 4*(2t+hi_dst)+j0 from half j1.
static __device__ inline void sig_pack(const f32x16 a, bf16x8 &f0, bf16x8 &f1) {
    unsigned s01 = sgpack2(a[0],  a[1]);   // rows (0,1)+4hi
    unsigned s23 = sgpack2(a[2],  a[3]);   // rows (2,3)+4hi
    unsigned s45 = sgpack2(a[4],  a[5]);   // rows (8,9)+4hi
    unsigned s67 = sgpack2(a[6],  a[7]);   // rows (10,11)+4hi
    unsigned s89 = sgpack2(a[8],  a[9]);   // rows (16,17)+4hi
    unsigned sAB = sgpack2(a[10], a[11]);  // rows (18,19)+4hi
    unsigned sCD = sgpack2(a[12], a[13]);  // rows (24,25)+4hi
    unsigned sEF = sgpack2(a[14], a[15]);  // rows (26,27)+4hi
    pl32swap(s01, s45);   // s01 -> f0 j=0,1 ; s45 -> f0 j=4,5
    pl32swap(s23, s67);   // s23 -> f0 j=2,3 ; s67 -> f0 j=6,7
    pl32swap(s89, sCD);   // f1 j=0,1 / j=4,5
    pl32swap(sAB, sEF);   // f1 j=2,3 / j=6,7
    uint4v t0 = {s01, s23, s45, s67};
    uint4v t1 = {s89, sAB, sCD, sEF};
    f0 = __builtin_bit_cast(bf16x8, t0);
    f1 = __builtin_bit_cast(bf16x8, t1);
}

// Transposed-orientation MFMA MLP; activations never touch LDS.
//   L1: h1^T = mfma(W1T(lds), xT)          (K=16: 15 inputs + b1 slot)
//   L2: h2^T = mfma(W2T(lds), h1T(reg))    (8 K-steps + b2 K-step from w2t pad)
//   L3: out^T = mfma(W3T(reg), h2T(reg))   (8 K-steps) + b3 at store
__global__ __launch_bounds__(256, 2)
void mlp256_kernel(const float* __restrict__ x,
                   const float* __restrict__ W1, const float* __restrict__ b1,
                   const float* __restrict__ W2, const float* __restrict__ b2,
                   const float* __restrict__ W3, const float* __restrict__ b3,
                   float* __restrict__ dst, int transposed)
{
    __shared__ __align__(16) unsigned short w1t[HDIM * SW1];
    __shared__ __align__(16) unsigned short w2t[HDIM * SW2];

    const int tid  = threadIdx.x;
    const int wave = tid >> 6;
    const int lane = tid & 63;
    const int l31  = lane & 31;
    const int hi   = lane >> 5;

    const int gid = blockIdx.x;
    const int e   = gid >> 2;          // NRG=4 consecutive blocks share one expert
    const int rg  = gid & (NRG - 1);
    const int rowbase = rg * ROWSPG;

    const float* w1p = W1 + e * (D_IN * HDIM);
    const float* b1p = b1 + e * HDIM;
    const float* w2p = W2 + e * (HDIM * HDIM);
    const float* b2p = b2 + e * HDIM;
    const float* w3p = W3 + e * HDIM;
    const float  b3v = b3[e];

    // ---- stage W1^T (+b1 in k=15) ----
    for (int i = tid; i < HDIM * 16; i += 256) {
        int h = i & 127, k = i >> 7;
        float v = (k < D_IN) ? w1p[k * HDIM + h] : b1p[h];
        w1t[h * SW1 + k] = (unsigned short)f2bf(v);
    }
    // ---- stage W2^T cols 0..127 ----
    for (int i = tid; i < HDIM * HDIM; i += 256) {
        int h = i & 127, k = i >> 7;
        w2t[h * SW2 + k] = (unsigned short)f2bf(w2p[k * HDIM + h]);
    }
    // ---- stage cols 128..143: b2 at k=128, zeros after (bias K-step reads k=128..143) ----
    for (int i = tid; i < HDIM * 16; i += 256) {
        int h = i >> 4, kk = i & 15;
        w2t[h * SW2 + 128 + kk] = (kk == 0) ? (unsigned short)f2bf(b2p[h]) : (unsigned short)0;
    }

    // ---- persistent register fragments ----
    bf16x8 ONEB;   // B-frag with 1.0 at k'==0 (partners the b2 K-step)
#pragma unroll
    for (int j = 0; j < 8; ++j) ONEB[j] = 0;
    if (hi == 0) ONEB[0] = f2bf(1.0f);

    bf16x8 W3A[8]; // A-frags with only row o==0 nonzero
#pragma unroll
    for (int ks = 0; ks < 8; ++ks) {
#pragma unroll
        for (int j = 0; j < 8; ++j) W3A[ks][j] = 0;
        if (l31 == 0) {
#pragma unroll
            for (int j = 0; j < 8; ++j)
                W3A[ks][j] = f2bf(w3p[ks * 16 + hi * 8 + j]);
        }
    }

    __syncthreads();   // weights staged; waves independent from here

    for (int c = wave; c < NCHUNK; c += 4) {
        const int r0 = rowbase + c * 32;
        const int bb = r0 + l31;

        // x B-frag: col b = l31, k = hi*8+j; slot k==15 = 1.0 (b1 partner)
        bf16x8 XB;
        {
            const float* xp = x + (size_t)bb * D_IN;
#pragma unroll
            for (int j = 0; j < 8; ++j) {
                int k = hi * 8 + j;
                float v = (k < D_IN) ? xp[k] : 1.0f;
                XB[j] = f2bf(v);
            }
        }

        // ---- layer 1 ----
        f32x16 acc1[4];
#pragma unroll
        for (int mf = 0; mf < 4; ++mf) {
            bf16x8 wa = *reinterpret_cast<const bf16x8*>(w1t + (mf * 32 + l31) * SW1 + hi * 8);
            acc1[mf] = MFMA(wa, XB, zero16());
        }

        // sigmoid -> in-register B-frags for layer 2
        bf16x8 hb[8];
#pragma unroll
        for (int mf = 0; mf < 4; ++mf)
            sig_pack(acc1[mf], hb[2 * mf], hb[2 * mf + 1]);

        // ---- layer 2 (8 K-steps + bias step) ----
        f32x16 acc2[4];
#pragma unroll
        for (int mf = 0; mf < 4; ++mf) acc2[mf] = zero16();
#pragma unroll
        for (int ks = 0; ks < 8; ++ks) {
#pragma unroll
            for (int mf = 0; mf < 4; ++mf) {
                bf16x8 wa = *reinterpret_cast<const bf16x8*>(w2t + (mf * 32 + l31) * SW2 + ks * 16 + hi * 8);
                acc2[mf] = MFMA(wa, hb[ks], acc2[mf]);
            }
        }
#pragma unroll
        for (int mf = 0; mf < 4; ++mf) {
            bf16x8 wa = *reinterpret_cast<const bf16x8*>(w2t + (mf * 32 + l31) * SW2 + 128 + hi * 8);
            acc2[mf] = MFMA(wa, ONEB, acc2[mf]);
        }

        // sigmoid -> in-register B-frags for layer 3 (reuse hb)
#pragma unroll
        for (int mf = 0; mf < 4; ++mf)
            sig_pack(acc2[mf], hb[2 * mf], hb[2 * mf + 1]);

        // ---- layer 3 ----
        f32x16 acc3 = zero16();
#pragma unroll
        for (int ks = 0; ks < 8; ++ks)
            acc3 = MFMA(W3A[ks], hb[ks], acc3);

        if (hi == 0) {
            float v = acc3[0] + b3v;   // row 0 = reg 0, hi==0 lanes
            if (transposed) dst[(size_t)e * BATCH + r0 + l31] = v;          // coalesced
            else            dst[(size_t)(r0 + l31) * E_CNT + e] = v;        // fallback
        }
    }
}

// wsT[e][b] (256 x 8192) -> out[b][e] (8192 x 256), 64x64 LDS tiles
__global__ __launch_bounds__(256)
void transpose_out_kernel(const float* __restrict__ wsT, float* __restrict__ out)
{
    __shared__ float tile[64][65];
    const int tx = threadIdx.x & 63;
    const int ty = threadIdx.x >> 6;
    const int b0 = blockIdx.x * 64;
    const int e0 = blockIdx.y * 64;
#pragma unroll
    for (int r = ty; r < 64; r += 4)
        tile[r][tx] = wsT[(size_t)(e0 + r) * BATCH + b0 + tx];
    __syncthreads();
#pragma unroll
    for (int r = ty; r < 64; r += 4)
        out[(size_t)(b0 + r) * E_CNT + e0 + tx] = tile[tx][r];
}

extern "C" void kernel_launch(void* const* d_in, const int* in_sizes, int n_in,
                              void* d_out, int out_size, void* d_ws, size_t ws_size,
                              hipStream_t stream) {
    const float* x  = (const float*)d_in[0];
    const float* W1 = (const float*)d_in[1];
    const float* b1 = (const float*)d_in[2];
    const float* W2 = (const float*)d_in[3];
    const float* b2 = (const float*)d_in[4];
    const float* W3 = (const float*)d_in[5];
    const float* b3 = (const float*)d_in[6];
    float* out = (float*)d_out;

    const bool use_ws = ws_size >= (size_t)E_CNT * BATCH * sizeof(float);
    if (use_ws) {
        mlp256_kernel<<<dim3(E_CNT * NRG), dim3(256), 0, stream>>>(
            x, W1, b1, W2, b2, W3, b3, (float*)d_ws, 1);
        transpose_out_kernel<<<dim3(BATCH / 64, E_CNT / 64), dim3(256), 0, stream>>>(
            (const float*)d_ws, out);
    } else {
        mlp256_kernel<<<dim3(E_CNT * NRG), dim3(256), 0, stream>>>(
            x, W1, b1, W2, b2, W3, b3, out, 0);
    }
}